// Round 4
// baseline (265.326 us; speedup 1.0000x reference)
//
#include <hip/hip_runtime.h>
#include <hip/hip_bf16.h>

#define BB 4
#define LL 1024
#define CC 768
#define HH 12
#define DD 64

typedef unsigned short ushort_t;
typedef __attribute__((ext_vector_type(8))) short bf16x8;
typedef __attribute__((ext_vector_type(4))) float f32x4;
typedef __attribute__((ext_vector_type(2))) float f32x2;
typedef __attribute__((ext_vector_type(2))) unsigned u32x2;

__device__ inline ushort_t f2bf(float x) {
    union { float f; unsigned u; } v; v.f = x;
    unsigned r = (v.u + 0x7FFFu + ((v.u >> 16) & 1u)) >> 16;
    return (ushort_t)r;
}
__device__ inline float u2f(unsigned u) {
    union { unsigned u; float f; } v; v.u = u;
    return v.f;
}
// pack two f32 -> packed 2xbf16 (RNE) via the HW cvt_pk path
__device__ inline unsigned pack2bf(float lo, float hi) {
    union { __hip_bfloat162 v; unsigned u; } r;
    r.v = __float22bfloat162_rn(make_float2(lo, hi));
    return r.u;
}

// Stage rows x 32 shorts from g (row stride `stride` shorts) into LDS,
// contiguous 64B rows, via async global->LDS (16B/lane, wave-uniform LDS base).
__device__ inline void stage_rows(const ushort_t* __restrict__ g, int stride,
                                  ushort_t* lds, int nbytes, int wave, int lane) {
    const int ko = (lane & 3) << 3;
    const int rsub = lane >> 2;
    for (int off = wave * 1024; off < nbytes; off += 4096) {
        int row = (off >> 6) + rsub;
        __builtin_amdgcn_global_load_lds(
            (const __attribute__((address_space(1))) void*)(g + (size_t)row * stride + ko),
            (__attribute__((address_space(3))) void*)(lds + (off >> 1)),
            16, 0, 0);
    }
}

// ---------------- prep: cast inputs + cast/transpose weights + zero Z (one launch) --------
__global__ __launch_bounds__(256) void prep(const float* __restrict__ q, const float* __restrict__ kv,
                                            const float* __restrict__ w0, const float* __restrict__ w1,
                                            const float* __restrict__ w2, const float* __restrict__ w3,
                                            ushort_t* __restrict__ qo, ushort_t* __restrict__ kvo,
                                            ushort_t* __restrict__ o0, ushort_t* __restrict__ o1,
                                            ushort_t* __restrict__ o2, ushort_t* __restrict__ o3,
                                            float* __restrict__ Zp) {
    __shared__ float t[32][33];
    const int bx = blockIdx.x;
    if (bx < 3072) {
        const float* src = bx < 1536 ? q : kv;
        ushort_t* dst = bx < 1536 ? qo : kvo;
        int bb = bx < 1536 ? bx : bx - 1536;
        size_t i = ((size_t)bb * 256 + threadIdx.x) * 8;
        float4 a = *(const float4*)(src + i);
        float4 b = *(const float4*)(src + i + 4);
        ushort_t u[8] = {f2bf(a.x), f2bf(a.y), f2bf(a.z), f2bf(a.w),
                         f2bf(b.x), f2bf(b.y), f2bf(b.z), f2bf(b.w)};
        *(uint4*)(dst + i) = *(uint4*)u;
    } else if (bx < 5376) {
        int w = bx - 3072;
        int z = w / 576, rem = w % 576;
        const float* W = z == 0 ? w0 : z == 1 ? w1 : z == 2 ? w2 : w3;
        ushort_t* Wt   = z == 0 ? o0 : z == 1 ? o1 : z == 2 ? o2 : o3;
        const int c = threadIdx.x & 31, r0 = threadIdx.x >> 5;
        const int kb = (rem / 24) * 32, nb = (rem % 24) * 32;
#pragma unroll
        for (int i = 0; i < 4; ++i)
            t[r0 + 8 * i][c] = W[(size_t)(kb + r0 + 8 * i) * CC + nb + c];
        __syncthreads();
#pragma unroll
        for (int i = 0; i < 4; ++i)
            Wt[(size_t)(nb + r0 + 8 * i) * CC + kb + c] = f2bf(t[c][r0 + 8 * i]);
    } else {
        // zero softmax denominators: 4*12*1024 floats over 192 blocks
        Zp[(bx - 5376) * 256 + threadIdx.x] = 0.f;
    }
}

// ---------------- fused Q/K/V projection (MFMA bf16), z picks target ----------------
// Q and K are written PRE-TILED in MFMA-fragment order:
//   per (b,h) plane of 64K elems: off = ((l>>4)*8 + (d>>3))*128 + (l&15)*8 + (d&7)
// so qk_premix can load fragments as contiguous 1KB wave-reads with no LDS.
__global__ __launch_bounds__(256) void proj_gemm(const ushort_t* __restrict__ Aq,
                                                 const ushort_t* __restrict__ Akv,
                                                 const ushort_t* __restrict__ Wqt,
                                                 const ushort_t* __restrict__ Wkt,
                                                 const ushort_t* __restrict__ Wvt,
                                                 ushort_t* __restrict__ Qo,
                                                 ushort_t* __restrict__ Ko,
                                                 ushort_t* __restrict__ Vto) {
    const int z = blockIdx.z;
    const ushort_t* A  = (z == 0) ? Aq : Akv;
    const ushort_t* Wt = (z == 0) ? Wqt : (z == 1 ? Wkt : Wvt);

    __shared__ __align__(16) ushort_t a_lds[128 * 32];
    __shared__ __align__(16) ushort_t b_lds[128 * 32];

    const int tid = threadIdx.x;
    const int bm = blockIdx.x * 128, bn = blockIdx.y * 128;
    const int wave = tid >> 6, lane = tid & 63;
    const int quad = lane >> 4, lq = lane & 15;
    const int wr = wave >> 1, wc = wave & 1;

    f32x4 acc[4][4] = {};

    for (int k0 = 0; k0 < CC; k0 += 32) {
        stage_rows(A + (size_t)bm * CC + k0, CC, a_lds, 8192, wave, lane);
        stage_rows(Wt + (size_t)bn * CC + k0, CC, b_lds, 8192, wave, lane);
        __syncthreads();
        bf16x8 af[4], bfr[4];
#pragma unroll
        for (int mi = 0; mi < 4; ++mi)
            af[mi] = *(bf16x8*)&a_lds[(wr * 64 + mi * 16 + lq) * 32 + quad * 8];
#pragma unroll
        for (int ni = 0; ni < 4; ++ni)
            bfr[ni] = *(bf16x8*)&b_lds[(wc * 64 + ni * 16 + lq) * 32 + quad * 8];
#pragma unroll
        for (int mi = 0; mi < 4; ++mi)
#pragma unroll
            for (int ni = 0; ni < 4; ++ni)
                acc[mi][ni] = __builtin_amdgcn_mfma_f32_16x16x32_bf16(af[mi], bfr[ni], acc[mi][ni], 0, 0, 0);
        __syncthreads();
    }

    const float scale = (z == 0) ? 0.125f : 1.0f;
#pragma unroll
    for (int mi = 0; mi < 4; ++mi)
#pragma unroll
        for (int ni = 0; ni < 4; ++ni)
#pragma unroll
            for (int r = 0; r < 4; ++r) {
                int row = bm + wr * 64 + mi * 16 + quad * 4 + r;  // b*1024 + l(or k)
                int col = bn + wc * 64 + ni * 16 + lq;            // h*64 + d
                int b = row >> 10, l = row & 1023, h = col >> 6, d = col & 63;
                ushort_t v = f2bf(acc[mi][ni][r] * scale);
                if (z == 2) {
                    Vto[((size_t)(b * HH + h) * DD + d) * LL + l] = v;
                } else {
                    size_t off = (size_t)(b * HH + h) * (LL * DD)
                               + (size_t)(((l >> 4) * 8 + (d >> 3)) * 128 + (l & 15) * 8 + (d & 7));
                    if (z == 0) Qo[off] = v;
                    else        Ko[off] = v;
                }
            }
}

// ---------------- QK^T fused with premix + exp + denominator accumulation ----------------
// Barrier-free, LDS-free: Q/K arrive pre-tiled in fragment order, so each wave's
// MFMA operands are contiguous 1KB global loads (served from L2: blockIdx is
// swizzled so each XCD-pair owns one batch b, K+Q per b = 3MB < 4MB L2).
// Per block: 32x32 (k,l) tile, all 12 heads in fp32 acc; premix thread-local;
// E = exp(premix(S^T)) stored bf16 [b][k][l][12] via nontemporal stores (keeps
// the streaming 96MB write from evicting Q/K out of L2).
__global__ __launch_bounds__(256) void qk_premix(const ushort_t* __restrict__ Qf,
                                                 const ushort_t* __restrict__ Kf,
                                                 const float* __restrict__ Wpre,
                                                 ushort_t* __restrict__ E,
                                                 float* __restrict__ Z) {
    const int tid = threadIdx.x;
    const int lane = tid & 63, wave = tid >> 6;
    const int quad = lane >> 4, lq = lane & 15;
    const int wr = wave >> 1, wc = wave & 1;

    // XCD-aware decode: xcd = x%8 (round-robin dispatch); each XCD-pair owns one b.
    const int x = blockIdx.x;
    const int xcd = x & 7;
    const int b = xcd >> 1;                           // 0..3
    const int s = x >> 3;                             // 0..511
    const int bk = (s & 31) << 5;                     // k-tile base
    const int bl = ((((s >> 5) << 1) | (xcd & 1))) << 5;  // l-tile base

    // fragment bases: per (b,h) plane LL*DD elems; k16-block = 1024 elems (2KB)
    const ushort_t* Kp = Kf + (size_t)b * HH * LL * DD
                       + (size_t)(((bk >> 4) + wr) * 1024 + quad * 128 + lq * 8);
    const ushort_t* Qp = Qf + (size_t)b * HH * LL * DD
                       + (size_t)(((bl >> 4) + wc) * 1024 + quad * 128 + lq * 8);

    f32x4 acc[HH] = {};
#pragma unroll
    for (int h = 0; h < HH; ++h) {
        const size_t ho = (size_t)h * (LL * DD);
        bf16x8 ka0 = *(const bf16x8*)(Kp + ho);
        bf16x8 ka1 = *(const bf16x8*)(Kp + ho + 512);
        bf16x8 qb0 = *(const bf16x8*)(Qp + ho);
        bf16x8 qb1 = *(const bf16x8*)(Qp + ho + 512);
        acc[h] = __builtin_amdgcn_mfma_f32_16x16x32_bf16(ka0, qb0, acc[h], 0, 0, 0);
        acc[h] = __builtin_amdgcn_mfma_f32_16x16x32_bf16(ka1, qb1, acc[h], 0, 0, 0);
    }

    // premix (fp32, thread-local across heads) + exp + pack bf16 pairs (heads 2i,2i+1)
    unsigned pk[6][4];
#pragma unroll
    for (int i2 = 0; i2 < 6; ++i2) {
        f32x4 m0 = {}, m1 = {};
#pragma unroll
        for (int h = 0; h < HH; ++h) {
            m0 += acc[h] * Wpre[h * HH + 2 * i2];
            m1 += acc[h] * Wpre[h * HH + 2 * i2 + 1];
        }
#pragma unroll
        for (int r = 0; r < 4; ++r)
            pk[i2][r] = pack2bf(__expf(m0[r]), __expf(m1[r]));
    }

    // denominator partials from ROUNDED values: sum this thread's 4 k-rows,
    // reduce across quads (k groups), atomically add per (i, l).
    float zp[HH];
#pragma unroll
    for (int i2 = 0; i2 < 6; ++i2) {
        float s0 = 0.f, s1 = 0.f;
#pragma unroll
        for (int r = 0; r < 4; ++r) {
            s0 += u2f(pk[i2][r] << 16);
            s1 += u2f(pk[i2][r] & 0xFFFF0000u);
        }
        zp[2 * i2] = s0; zp[2 * i2 + 1] = s1;
    }
#pragma unroll
    for (int i = 0; i < HH; ++i) {
        zp[i] += __shfl_xor(zp[i], 16);
        zp[i] += __shfl_xor(zp[i], 32);
    }
    if (quad == 0) {
#pragma unroll
        for (int i = 0; i < HH; ++i)
            atomicAdd(&Z[((size_t)b * HH + i) * LL + bl + wc * 16 + lq], zp[i]);
    }

    // store E[b][k][l][12]: 24B (12 heads) per (k,l) position, head-contiguous, NT
#pragma unroll
    for (int r = 0; r < 4; ++r) {
        ushort_t* ep = E + (((size_t)b * LL + bk + wr * 16 + quad * 4 + r) * LL
                            + bl + wc * 16 + lq) * HH;
        u32x2 s0; s0.x = pk[0][r]; s0.y = pk[1][r];
        u32x2 s1; s1.x = pk[2][r]; s1.y = pk[3][r];
        u32x2 s2; s2.x = pk[4][r]; s2.y = pk[5][r];
        __builtin_nontemporal_store(s0, (u32x2*)ep);
        __builtin_nontemporal_store(s1, (u32x2*)(ep + 4));
        __builtin_nontemporal_store(s2, (u32x2*)(ep + 8));
    }
}

// ---------------- PV fused with normalize + postmix (v2: no V staging) ----------------
// Block = (b, 16 l-rows), 512 threads / 8 waves, all 12 output heads.
// V fragments load DIRECTLY from global (Vt[d][k] rows are fragment-contiguous;
// V per b = 1.5MB, L2-resident via XCD-pair pinning). E loads are nontemporal
// (read-once stream, don't evict V) and prefetched one kt ahead into registers.
// p_lds is double-buffered; ONE raw barrier per kt (lgkmcnt only, vmcnt stays
// in flight across it, unlike __syncthreads).
__global__ __launch_bounds__(512) void pv_postmix(const ushort_t* __restrict__ E,
                                                  const ushort_t* __restrict__ Vt,
                                                  const float* __restrict__ Wpost,
                                                  const float* __restrict__ Z,
                                                  ushort_t* __restrict__ att) {
    __shared__ __align__(16) ushort_t p_lds[2][HH * 16 * 64];  // 2 x 24KB, XOR-swizzled

    const int tid = threadIdx.x;
    const int lane = tid & 63, wave = tid >> 6;
    const int quad = lane >> 4, lq = lane & 15;
    const int ig = (wave >> 2) * 6;            // head-group base (0 or 6)
    const int wd = wave & 3;                   // d-quadrant (16 cols)
    const int lmix = tid & 15, kp = tid >> 4;  // mixing role: l row, k-pair 0..31

    // XCD-aware decode: 256 blocks, xcd=bid&7; each XCD-pair owns one b (V L2-resident)
    const int bid = blockIdx.x;
    const int xcd = bid & 7;
    const int b = xcd >> 1;                                 // 0..3
    const int bl = ((((bid >> 3) << 1) | (xcd & 1))) << 4;  // l-tile base (16 rows)

    float invZ[HH];
#pragma unroll
    for (int h = 0; h < HH; ++h)
        invZ[h] = 1.0f / Z[((size_t)b * HH + h) * LL + bl + lmix];

    // V fragment base for this wave's (d-col = wd*16+lq) rows
    const size_t vrow = ((size_t)(b * HH) * DD + wd * 16 + lq) * LL;
    // E base for this thread's (l = bl+lmix, k = kp*2) role
    const ushort_t* ebase = E + (((size_t)b * LL + kp * 2) * LL + bl + lmix) * HH;
    const size_t estep = (size_t)LL * HH;   // one k step

    f32x4 acc[6] = {};
    u32x2 er[6];

    // prologue: E loads for kt=0
#pragma unroll
    for (int j = 0; j < 3; ++j) {
        er[j]     = __builtin_nontemporal_load((const u32x2*)(ebase + 4 * j));
        er[j + 3] = __builtin_nontemporal_load((const u32x2*)(ebase + estep + 4 * j));
    }

#pragma unroll 1
    for (int kt = 0; kt < 16; ++kt) {
        // ---- postmix current E regs: normalize + cross-head mix (packed f32)
        unsigned w0[6] = {er[0].x, er[0].y, er[1].x, er[1].y, er[2].x, er[2].y};
        unsigned w1[6] = {er[3].x, er[3].y, er[4].x, er[4].y, er[5].x, er[5].y};
        f32x2 m[HH] = {};
#pragma unroll
        for (int h2 = 0; h2 < 6; ++h2) {
            f32x2 pe, po;
            pe.x = u2f(w0[h2] << 16);           pe.y = u2f(w1[h2] << 16);
            po.x = u2f(w0[h2] & 0xFFFF0000u);   po.y = u2f(w1[h2] & 0xFFFF0000u);
            pe *= invZ[2 * h2];
            po *= invZ[2 * h2 + 1];
#pragma unroll
            for (int i = 0; i < HH; ++i) {
                m[i] += pe * Wpost[(2 * h2) * HH + i];
                m[i] += po * Wpost[(2 * h2 + 1) * HH + i];
            }
        }

        // ---- issue E prefetch for kt+1 (in flight across the raw barrier)
        if (kt < 15) {
            const ushort_t* ep = ebase + (size_t)(kt + 1) * 64 * estep;
#pragma unroll
            for (int j = 0; j < 3; ++j) {
                er[j]     = __builtin_nontemporal_load((const u32x2*)(ep + 4 * j));
                er[j + 3] = __builtin_nontemporal_load((const u32x2*)(ep + estep + 4 * j));
            }
        }

        // ---- write mixed P to swizzled LDS (buf = kt&1)
        {
            const int cs = (kp >> 2) ^ (lmix & 7);
            unsigned* pw = (unsigned*)p_lds[kt & 1];
#pragma unroll
            for (int i = 0; i < HH; ++i)
                pw[(i * 16 + lmix) * 32 + cs * 4 + (kp & 3)] = pack2bf(m[i].x, m[i].y);
        }

        // ---- raw barrier: drain LDS writes only; global loads stay in flight
        asm volatile("s_waitcnt lgkmcnt(0)" ::: "memory");
        __builtin_amdgcn_s_barrier();
        asm volatile("" ::: "memory");

        // ---- MFMA: O_i[16 l][16 d] += P_i x V_i over K=64; V direct from global (L2)
        const ushort_t* pb = p_lds[kt & 1];
#pragma unroll
        for (int k0 = 0; k0 < 2; ++k0)
#pragma unroll
            for (int ii = 0; ii < 6; ++ii) {
                const int hh = ig + ii;
                const int chl = (k0 << 2) + quad;            // logical k-chunk
                const int chs = chl ^ (lq & 7);              // swizzled LDS chunk
                bf16x8 pa  = *(bf16x8*)&pb[(hh * 16 + lq) * 64 + chs * 8];
                bf16x8 vbf = *(const bf16x8*)(Vt + vrow + (size_t)hh * (DD * LL)
                                              + kt * 64 + chl * 8);
                acc[ii] = __builtin_amdgcn_mfma_f32_16x16x32_bf16(pa, vbf, acc[ii], 0, 0, 0);
            }
        // no second barrier: double-buffered p_lds; lgkmcnt(0)+barrier of the NEXT
        // iteration orders reads-of-buf before its overwrite two iterations later
    }

#pragma unroll
    for (int ii = 0; ii < 6; ++ii)
#pragma unroll
        for (int r = 0; r < 4; ++r)
            att[((size_t)b * LL + bl + quad * 4 + r) * CC + (ig + ii) * 64 + wd * 16 + lq] =
                f2bf(acc[ii][r]);
}

// ---------------- out = att @ Wout (MFMA, fp32 out). BM=128, BN=64 -> 384 blocks ----------------
__global__ __launch_bounds__(256) void out_gemm(const ushort_t* __restrict__ A,
                                                const ushort_t* __restrict__ Wt,
                                                float* __restrict__ out) {
    __shared__ __align__(16) ushort_t a_lds[128 * 32];
    __shared__ __align__(16) ushort_t b_lds[64 * 32];

    const int tid = threadIdx.x;
    const int bm = blockIdx.x * 128, bn = blockIdx.y * 64;
    const int wave = tid >> 6, lane = tid & 63;
    const int quad = lane >> 4, lq = lane & 15;
    const int wr = wave >> 1, wc = wave & 1;

    f32x4 acc[4][2] = {};

    for (int k0 = 0; k0 < CC; k0 += 32) {
        stage_rows(A + (size_t)bm * CC + k0, CC, a_lds, 8192, wave, lane);
        stage_rows(Wt + (size_t)bn * CC + k0, CC, b_lds, 4096, wave, lane);
        __syncthreads();
        bf16x8 af[4], bfr[2];
#pragma unroll
        for (int mi = 0; mi < 4; ++mi)
            af[mi] = *(bf16x8*)&a_lds[(wr * 64 + mi * 16 + lq) * 32 + quad * 8];
#pragma unroll
        for (int ni = 0; ni < 2; ++ni)
            bfr[ni] = *(bf16x8*)&b_lds[(wc * 32 + ni * 16 + lq) * 32 + quad * 8];
#pragma unroll
        for (int mi = 0; mi < 4; ++mi)
#pragma unroll
            for (int ni = 0; ni < 2; ++ni)
                acc[mi][ni] = __builtin_amdgcn_mfma_f32_16x16x32_bf16(af[mi], bfr[ni], acc[mi][ni], 0, 0, 0);
        __syncthreads();
    }

#pragma unroll
    for (int mi = 0; mi < 4; ++mi)
#pragma unroll
        for (int ni = 0; ni < 2; ++ni)
#pragma unroll
            for (int r = 0; r < 4; ++r) {
                int row = bm + wr * 64 + mi * 16 + quad * 4 + r;
                int col = bn + wc * 32 + ni * 16 + lq;
                out[(size_t)row * CC + col] = acc[mi][ni][r];
            }
}

// ---------------- Launch ----------------
extern "C" void kernel_launch(void* const* d_in, const int* in_sizes, int n_in,
                              void* d_out, int out_size, void* d_ws, size_t ws_size,
                              hipStream_t stream) {
    const float* inputs_q  = (const float*)d_in[0];
    const float* inputs_kv = (const float*)d_in[1];
    const float* Wq   = (const float*)d_in[2];
    const float* Wk   = (const float*)d_in[3];
    const float* Wv   = (const float*)d_in[4];
    const float* Wout = (const float*)d_in[5];
    const float* Wpre  = (const float*)d_in[6];
    const float* Wpost = (const float*)d_in[7];
    float* out = (float*)d_out;

    const size_t nS   = (size_t)BB * HH * LL * LL;   // E: [b][k][l][12]
    const size_t nQKV = (size_t)BB * HH * LL * DD;
    const size_t nW   = (size_t)CC * CC;

    ushort_t* Eb   = (ushort_t*)d_ws;
    ushort_t* Qb   = Eb + nS;
    ushort_t* Kb   = Qb + nQKV;
    ushort_t* Vtb  = Kb + nQKV;
    ushort_t* attb = Vtb + nQKV;
    ushort_t* inq  = attb + nQKV;
    ushort_t* inkv = inq + nQKV;
    ushort_t* Wqt  = inkv + nQKV;
    ushort_t* Wkt  = Wqt + nW;
    ushort_t* Wvt  = Wkt + nW;
    ushort_t* Wot  = Wvt + nW;
    float*    Zb   = (float*)(Wot + nW);             // [b][h][l] fp32, 192KB

    dim3 blk(256);

    prep<<<dim3(5568), blk, 0, stream>>>(inputs_q, inputs_kv, Wq, Wk, Wv, Wout,
                                         inq, inkv, Wqt, Wkt, Wvt, Wot, Zb);
    proj_gemm<<<dim3(32, 6, 3), blk, 0, stream>>>(inq, inkv, Wqt, Wkt, Wvt, Qb, Kb, Vtb);
    qk_premix<<<dim3(4096), blk, 0, stream>>>(Qb, Kb, Wpre, Eb, Zb);
    pv_postmix<<<dim3(256), dim3(512), 0, stream>>>(Eb, Vtb, Wpost, Zb, attb);
    out_gemm<<<dim3(32, 12), blk, 0, stream>>>(attb, Wot, out);
}

// Round 5
// 264.602 us; speedup vs baseline: 1.0027x; 1.0027x over previous
//
#include <hip/hip_runtime.h>
#include <hip/hip_bf16.h>

#define BB 4
#define LL 1024
#define CC 768
#define HH 12
#define DD 64

typedef unsigned short ushort_t;
typedef __attribute__((ext_vector_type(8))) short bf16x8;
typedef __attribute__((ext_vector_type(4))) float f32x4;
typedef __attribute__((ext_vector_type(2))) float f32x2;
typedef __attribute__((ext_vector_type(2))) unsigned u32x2;

__device__ inline ushort_t f2bf(float x) {
    union { float f; unsigned u; } v; v.f = x;
    unsigned r = (v.u + 0x7FFFu + ((v.u >> 16) & 1u)) >> 16;
    return (ushort_t)r;
}
__device__ inline float u2f(unsigned u) {
    union { unsigned u; float f; } v; v.u = u;
    return v.f;
}
// pack two f32 -> packed 2xbf16 (RNE) via the HW cvt_pk path
__device__ inline unsigned pack2bf(float lo, float hi) {
    union { __hip_bfloat162 v; unsigned u; } r;
    r.v = __float22bfloat162_rn(make_float2(lo, hi));
    return r.u;
}

// Stage rows x 32 shorts from g (row stride `stride` shorts) into LDS,
// contiguous 64B rows, via async global->LDS (16B/lane, wave-uniform LDS base).
__device__ inline void stage_rows(const ushort_t* __restrict__ g, int stride,
                                  ushort_t* lds, int nbytes, int wave, int lane) {
    const int ko = (lane & 3) << 3;
    const int rsub = lane >> 2;
    for (int off = wave * 1024; off < nbytes; off += 4096) {
        int row = (off >> 6) + rsub;
        __builtin_amdgcn_global_load_lds(
            (const __attribute__((address_space(1))) void*)(g + (size_t)row * stride + ko),
            (__attribute__((address_space(3))) void*)(lds + (off >> 1)),
            16, 0, 0);
    }
}

// ---------------- prep: cast inputs + cast/transpose weights + zero Z (one launch) --------
__global__ __launch_bounds__(256) void prep(const float* __restrict__ q, const float* __restrict__ kv,
                                            const float* __restrict__ w0, const float* __restrict__ w1,
                                            const float* __restrict__ w2, const float* __restrict__ w3,
                                            ushort_t* __restrict__ qo, ushort_t* __restrict__ kvo,
                                            ushort_t* __restrict__ o0, ushort_t* __restrict__ o1,
                                            ushort_t* __restrict__ o2, ushort_t* __restrict__ o3,
                                            float* __restrict__ Zp) {
    __shared__ float t[32][33];
    const int bx = blockIdx.x;
    if (bx < 3072) {
        const float* src = bx < 1536 ? q : kv;
        ushort_t* dst = bx < 1536 ? qo : kvo;
        int bb = bx < 1536 ? bx : bx - 1536;
        size_t i = ((size_t)bb * 256 + threadIdx.x) * 8;
        float4 a = *(const float4*)(src + i);
        float4 b = *(const float4*)(src + i + 4);
        ushort_t u[8] = {f2bf(a.x), f2bf(a.y), f2bf(a.z), f2bf(a.w),
                         f2bf(b.x), f2bf(b.y), f2bf(b.z), f2bf(b.w)};
        *(uint4*)(dst + i) = *(uint4*)u;
    } else if (bx < 5376) {
        int w = bx - 3072;
        int z = w / 576, rem = w % 576;
        const float* W = z == 0 ? w0 : z == 1 ? w1 : z == 2 ? w2 : w3;
        ushort_t* Wt   = z == 0 ? o0 : z == 1 ? o1 : z == 2 ? o2 : o3;
        const int c = threadIdx.x & 31, r0 = threadIdx.x >> 5;
        const int kb = (rem / 24) * 32, nb = (rem % 24) * 32;
#pragma unroll
        for (int i = 0; i < 4; ++i)
            t[r0 + 8 * i][c] = W[(size_t)(kb + r0 + 8 * i) * CC + nb + c];
        __syncthreads();
#pragma unroll
        for (int i = 0; i < 4; ++i)
            Wt[(size_t)(nb + r0 + 8 * i) * CC + kb + c] = f2bf(t[c][r0 + 8 * i]);
    } else {
        // zero softmax denominators: 4*12*1024 floats over 192 blocks
        Zp[(bx - 5376) * 256 + threadIdx.x] = 0.f;
    }
}

// ---------------- fused Q/K/V projection (MFMA bf16), z picks target ----------------
// Q and K are written PRE-TILED in MFMA-fragment order:
//   per (b,h) plane of 64K elems: off = ((l>>4)*8 + (d>>3))*128 + (l&15)*8 + (d&7)
// so qk_premix can load fragments as contiguous 1KB wave-reads with no LDS.
__global__ __launch_bounds__(256) void proj_gemm(const ushort_t* __restrict__ Aq,
                                                 const ushort_t* __restrict__ Akv,
                                                 const ushort_t* __restrict__ Wqt,
                                                 const ushort_t* __restrict__ Wkt,
                                                 const ushort_t* __restrict__ Wvt,
                                                 ushort_t* __restrict__ Qo,
                                                 ushort_t* __restrict__ Ko,
                                                 ushort_t* __restrict__ Vto) {
    const int z = blockIdx.z;
    const ushort_t* A  = (z == 0) ? Aq : Akv;
    const ushort_t* Wt = (z == 0) ? Wqt : (z == 1 ? Wkt : Wvt);

    __shared__ __align__(16) ushort_t a_lds[128 * 32];
    __shared__ __align__(16) ushort_t b_lds[128 * 32];

    const int tid = threadIdx.x;
    const int bm = blockIdx.x * 128, bn = blockIdx.y * 128;
    const int wave = tid >> 6, lane = tid & 63;
    const int quad = lane >> 4, lq = lane & 15;
    const int wr = wave >> 1, wc = wave & 1;

    f32x4 acc[4][4] = {};

    for (int k0 = 0; k0 < CC; k0 += 32) {
        stage_rows(A + (size_t)bm * CC + k0, CC, a_lds, 8192, wave, lane);
        stage_rows(Wt + (size_t)bn * CC + k0, CC, b_lds, 8192, wave, lane);
        __syncthreads();
        bf16x8 af[4], bfr[4];
#pragma unroll
        for (int mi = 0; mi < 4; ++mi)
            af[mi] = *(bf16x8*)&a_lds[(wr * 64 + mi * 16 + lq) * 32 + quad * 8];
#pragma unroll
        for (int ni = 0; ni < 4; ++ni)
            bfr[ni] = *(bf16x8*)&b_lds[(wc * 64 + ni * 16 + lq) * 32 + quad * 8];
#pragma unroll
        for (int mi = 0; mi < 4; ++mi)
#pragma unroll
            for (int ni = 0; ni < 4; ++ni)
                acc[mi][ni] = __builtin_amdgcn_mfma_f32_16x16x32_bf16(af[mi], bfr[ni], acc[mi][ni], 0, 0, 0);
        __syncthreads();
    }

    const float scale = (z == 0) ? 0.125f : 1.0f;
#pragma unroll
    for (int mi = 0; mi < 4; ++mi)
#pragma unroll
        for (int ni = 0; ni < 4; ++ni)
#pragma unroll
            for (int r = 0; r < 4; ++r) {
                int row = bm + wr * 64 + mi * 16 + quad * 4 + r;  // b*1024 + l(or k)
                int col = bn + wc * 64 + ni * 16 + lq;            // h*64 + d
                int b = row >> 10, l = row & 1023, h = col >> 6, d = col & 63;
                ushort_t v = f2bf(acc[mi][ni][r] * scale);
                if (z == 2) {
                    Vto[((size_t)(b * HH + h) * DD + d) * LL + l] = v;
                } else {
                    size_t off = (size_t)(b * HH + h) * (LL * DD)
                               + (size_t)(((l >> 4) * 8 + (d >> 3)) * 128 + (l & 15) * 8 + (d & 7));
                    if (z == 0) Qo[off] = v;
                    else        Ko[off] = v;
                }
            }
}

// ---------------- QK^T fused with premix + exp + denominator accumulation ----------------
// Barrier-free, LDS-free: Q/K arrive pre-tiled in fragment order, so each wave's
// MFMA operands are contiguous 1KB global loads (served from L2: blockIdx is
// swizzled so each XCD-pair owns one batch b, K+Q per b = 3MB < 4MB L2).
__global__ __launch_bounds__(256) void qk_premix(const ushort_t* __restrict__ Qf,
                                                 const ushort_t* __restrict__ Kf,
                                                 const float* __restrict__ Wpre,
                                                 ushort_t* __restrict__ E,
                                                 float* __restrict__ Z) {
    const int tid = threadIdx.x;
    const int lane = tid & 63, wave = tid >> 6;
    const int quad = lane >> 4, lq = lane & 15;
    const int wr = wave >> 1, wc = wave & 1;

    // XCD-aware decode: xcd = x%8 (round-robin dispatch); each XCD-pair owns one b.
    const int x = blockIdx.x;
    const int xcd = x & 7;
    const int b = xcd >> 1;                           // 0..3
    const int s = x >> 3;                             // 0..511
    const int bk = (s & 31) << 5;                     // k-tile base
    const int bl = ((((s >> 5) << 1) | (xcd & 1))) << 5;  // l-tile base

    // fragment bases: per (b,h) plane LL*DD elems; k16-block = 1024 elems (2KB)
    const ushort_t* Kp = Kf + (size_t)b * HH * LL * DD
                       + (size_t)(((bk >> 4) + wr) * 1024 + quad * 128 + lq * 8);
    const ushort_t* Qp = Qf + (size_t)b * HH * LL * DD
                       + (size_t)(((bl >> 4) + wc) * 1024 + quad * 128 + lq * 8);

    f32x4 acc[HH] = {};
#pragma unroll
    for (int h = 0; h < HH; ++h) {
        const size_t ho = (size_t)h * (LL * DD);
        bf16x8 ka0 = *(const bf16x8*)(Kp + ho);
        bf16x8 ka1 = *(const bf16x8*)(Kp + ho + 512);
        bf16x8 qb0 = *(const bf16x8*)(Qp + ho);
        bf16x8 qb1 = *(const bf16x8*)(Qp + ho + 512);
        acc[h] = __builtin_amdgcn_mfma_f32_16x16x32_bf16(ka0, qb0, acc[h], 0, 0, 0);
        acc[h] = __builtin_amdgcn_mfma_f32_16x16x32_bf16(ka1, qb1, acc[h], 0, 0, 0);
    }

    // premix (fp32, thread-local across heads) + exp + pack bf16 pairs (heads 2i,2i+1)
    unsigned pk[6][4];
#pragma unroll
    for (int i2 = 0; i2 < 6; ++i2) {
        f32x4 m0 = {}, m1 = {};
#pragma unroll
        for (int h = 0; h < HH; ++h) {
            m0 += acc[h] * Wpre[h * HH + 2 * i2];
            m1 += acc[h] * Wpre[h * HH + 2 * i2 + 1];
        }
#pragma unroll
        for (int r = 0; r < 4; ++r)
            pk[i2][r] = pack2bf(__expf(m0[r]), __expf(m1[r]));
    }

    // denominator partials from ROUNDED values: sum this thread's 4 k-rows,
    // reduce across quads (k groups), atomically add per (i, l).
    float zp[HH];
#pragma unroll
    for (int i2 = 0; i2 < 6; ++i2) {
        float s0 = 0.f, s1 = 0.f;
#pragma unroll
        for (int r = 0; r < 4; ++r) {
            s0 += u2f(pk[i2][r] << 16);
            s1 += u2f(pk[i2][r] & 0xFFFF0000u);
        }
        zp[2 * i2] = s0; zp[2 * i2 + 1] = s1;
    }
#pragma unroll
    for (int i = 0; i < HH; ++i) {
        zp[i] += __shfl_xor(zp[i], 16);
        zp[i] += __shfl_xor(zp[i], 32);
    }
    if (quad == 0) {
#pragma unroll
        for (int i = 0; i < HH; ++i)
            atomicAdd(&Z[((size_t)b * HH + i) * LL + bl + wc * 16 + lq], zp[i]);
    }

    // store E[b][k][l][12]: 24B (12 heads) per (k,l) position, head-contiguous, NT
#pragma unroll
    for (int r = 0; r < 4; ++r) {
        ushort_t* ep = E + (((size_t)b * LL + bk + wr * 16 + quad * 4 + r) * LL
                            + bl + wc * 16 + lq) * HH;
        u32x2 s0; s0.x = pk[0][r]; s0.y = pk[1][r];
        u32x2 s1; s1.x = pk[2][r]; s1.y = pk[3][r];
        u32x2 s2; s2.x = pk[4][r]; s2.y = pk[5][r];
        __builtin_nontemporal_store(s0, (u32x2*)ep);
        __builtin_nontemporal_store(s1, (u32x2*)(ep + 4));
        __builtin_nontemporal_store(s2, (u32x2*)(ep + 8));
    }
}

// ---------------- PV fused with normalize + postmix (v3: head-split, 512 blocks) ----------
// Block = (b, 16 l-rows, head-group of 6), 256 threads / 4 waves = 4 d-quadrants.
// Grid 512 -> 2 independent blocks (barrier domains) per CU. The two blocks sharing
// (b, l-tile) differ only in head-group and sit on the SAME XCD (bids differ by 256),
// so their shared E slice is read from L2 by the second one (E loads are plain/cached).
// Per 64-k tile: E (prefetched 1 kt ahead in regs) -> normalize + postmix (6 out-heads)
// -> p_lds (double-buffered, 2x12KB) -> raw lgkm-only barrier -> MFMA with V fragments
// batch-loaded from global (L2-resident) into registers.
__global__ __launch_bounds__(256, 3) void pv_postmix(const ushort_t* __restrict__ E,
                                                     const ushort_t* __restrict__ Vt,
                                                     const float* __restrict__ Wpost,
                                                     const float* __restrict__ Z,
                                                     ushort_t* __restrict__ att) {
    __shared__ __align__(16) ushort_t p_lds[2][6 * 16 * 64];  // 2 x 12KB, XOR-swizzled

    const int tid = threadIdx.x;
    const int lane = tid & 63, wave = tid >> 6;
    const int quad = lane >> 4, lq = lane & 15;
    const int wd = wave;                       // d-quadrant (16 cols)
    const int lmix = tid & 15, kp = tid >> 4;  // mixing role: l row, k-quad 0..15

    // decode: 512 blocks; xcd = bid&7 -> b; s = bid>>3: hg = s>>5, ltile = (s&31)*2+(xcd&1)
    const int bid = blockIdx.x;
    const int xcd = bid & 7;
    const int b = xcd >> 1;
    const int s = bid >> 3;
    const int hg = s >> 5;                     // head-group 0/1
    const int ig = hg * 6;
    const int bl = ((((s & 31) << 1) | (xcd & 1))) << 4;  // l-tile base (16 rows)

    float invZ[HH];
#pragma unroll
    for (int h = 0; h < HH; ++h)
        invZ[h] = 1.0f / Z[((size_t)b * HH + h) * LL + bl + lmix];

    const size_t estep = (size_t)LL * HH;      // one k step in E
    const ushort_t* ebase = E + (((size_t)b * LL + kp * 4) * LL + bl + lmix) * HH;
    // V base: output head ig+ii uses V[ig+ii]; this wave covers d = wd*16+lq
    const size_t vbase = ((size_t)(b * HH + ig) * DD + wd * 16 + lq) * LL;

    f32x4 acc[6] = {};
    u32x2 er[12];

    // prologue: E regs for kt=0 (thread owns k = kp*4 .. kp*4+3 as 2 pair-units)
#pragma unroll
    for (int u = 0; u < 2; ++u)
#pragma unroll
        for (int j = 0; j < 3; ++j) {
            er[u * 6 + j]     = *(const u32x2*)(ebase + (size_t)(2 * u) * estep + 4 * j);
            er[u * 6 + 3 + j] = *(const u32x2*)(ebase + (size_t)(2 * u + 1) * estep + 4 * j);
        }

#pragma unroll 1
    for (int kt = 0; kt < 16; ++kt) {
        // ---- postmix both pair-units: normalize + mix 12 in-heads -> 6 out-heads
        unsigned pkw[2][6];
#pragma unroll
        for (int u = 0; u < 2; ++u) {
            unsigned w0[6] = {er[u*6+0].x, er[u*6+0].y, er[u*6+1].x, er[u*6+1].y, er[u*6+2].x, er[u*6+2].y};
            unsigned w1[6] = {er[u*6+3].x, er[u*6+3].y, er[u*6+4].x, er[u*6+4].y, er[u*6+5].x, er[u*6+5].y};
            f32x2 m[6] = {};
#pragma unroll
            for (int h2 = 0; h2 < 6; ++h2) {
                f32x2 pe, po;
                pe.x = u2f(w0[h2] << 16);           pe.y = u2f(w1[h2] << 16);
                po.x = u2f(w0[h2] & 0xFFFF0000u);   po.y = u2f(w1[h2] & 0xFFFF0000u);
                pe *= invZ[2 * h2];
                po *= invZ[2 * h2 + 1];
#pragma unroll
                for (int i = 0; i < 6; ++i) {
                    m[i] += pe * Wpost[(2 * h2) * HH + ig + i];
                    m[i] += po * Wpost[(2 * h2 + 1) * HH + ig + i];
                }
            }
#pragma unroll
            for (int i = 0; i < 6; ++i) pkw[u][i] = pack2bf(m[i].x, m[i].y);
        }

        // ---- issue E prefetch for kt+1 (er regs are dead; loads fly across barrier)
        if (kt < 15) {
            const ushort_t* ep = ebase + (size_t)(kt + 1) * 64 * estep;
#pragma unroll
            for (int u = 0; u < 2; ++u)
#pragma unroll
                for (int j = 0; j < 3; ++j) {
                    er[u * 6 + j]     = *(const u32x2*)(ep + (size_t)(2 * u) * estep + 4 * j);
                    er[u * 6 + 3 + j] = *(const u32x2*)(ep + (size_t)(2 * u + 1) * estep + 4 * j);
                }
        }

        // ---- write mixed P to swizzled LDS (buf = kt&1); word w = kp*2+u per row
        {
            unsigned* pw = (unsigned*)p_lds[kt & 1];
#pragma unroll
            for (int u = 0; u < 2; ++u) {
                const int w = kp * 2 + u;
                const int word = (((w >> 2) ^ (lmix & 7)) << 2) + (w & 3);
#pragma unroll
                for (int i = 0; i < 6; ++i)
                    pw[(i * 16 + lmix) * 32 + word] = pkw[u][i];
            }
        }

        // ---- raw barrier: drain LDS writes only; global loads stay in flight
        asm volatile("s_waitcnt lgkmcnt(0)" ::: "memory");
        __builtin_amdgcn_s_barrier();
        asm volatile("" ::: "memory");

        // ---- MFMA: O_i[16 l][16 d] += P_i x V_i over K=64; V batch-loaded per k0
        const ushort_t* pb = p_lds[kt & 1];
#pragma unroll
        for (int k0 = 0; k0 < 2; ++k0) {
            bf16x8 vf[6];
#pragma unroll
            for (int ii = 0; ii < 6; ++ii)
                vf[ii] = *(const bf16x8*)(Vt + vbase + (size_t)ii * (DD * LL)
                                          + kt * 64 + k0 * 32 + quad * 8);
            const int chs = ((k0 << 2) + quad) ^ (lq & 7);
#pragma unroll
            for (int ii = 0; ii < 6; ++ii) {
                bf16x8 pa = *(bf16x8*)&pb[(ii * 16 + lq) * 64 + chs * 8];
                acc[ii] = __builtin_amdgcn_mfma_f32_16x16x32_bf16(pa, vf[ii], acc[ii], 0, 0, 0);
            }
        }
    }

#pragma unroll
    for (int ii = 0; ii < 6; ++ii)
#pragma unroll
        for (int r = 0; r < 4; ++r)
            att[((size_t)b * LL + bl + quad * 4 + r) * CC + (ig + ii) * 64 + wd * 16 + lq] =
                f2bf(acc[ii][r]);
}

// ---------------- out = att @ Wout (MFMA, fp32 out). BM=128, BN=64 -> 384 blocks ----------------
__global__ __launch_bounds__(256) void out_gemm(const ushort_t* __restrict__ A,
                                                const ushort_t* __restrict__ Wt,
                                                float* __restrict__ out) {
    __shared__ __align__(16) ushort_t a_lds[128 * 32];
    __shared__ __align__(16) ushort_t b_lds[64 * 32];

    const int tid = threadIdx.x;
    const int bm = blockIdx.x * 128, bn = blockIdx.y * 64;
    const int wave = tid >> 6, lane = tid & 63;
    const int quad = lane >> 4, lq = lane & 15;
    const int wr = wave >> 1, wc = wave & 1;

    f32x4 acc[4][2] = {};

    for (int k0 = 0; k0 < CC; k0 += 32) {
        stage_rows(A + (size_t)bm * CC + k0, CC, a_lds, 8192, wave, lane);
        stage_rows(Wt + (size_t)bn * CC + k0, CC, b_lds, 4096, wave, lane);
        __syncthreads();
        bf16x8 af[4], bfr[2];
#pragma unroll
        for (int mi = 0; mi < 4; ++mi)
            af[mi] = *(bf16x8*)&a_lds[(wr * 64 + mi * 16 + lq) * 32 + quad * 8];
#pragma unroll
        for (int ni = 0; ni < 2; ++ni)
            bfr[ni] = *(bf16x8*)&b_lds[(wc * 32 + ni * 16 + lq) * 32 + quad * 8];
#pragma unroll
        for (int mi = 0; mi < 4; ++mi)
#pragma unroll
            for (int ni = 0; ni < 2; ++ni)
                acc[mi][ni] = __builtin_amdgcn_mfma_f32_16x16x32_bf16(af[mi], bfr[ni], acc[mi][ni], 0, 0, 0);
        __syncthreads();
    }

#pragma unroll
    for (int mi = 0; mi < 4; ++mi)
#pragma unroll
        for (int ni = 0; ni < 2; ++ni)
#pragma unroll
            for (int r = 0; r < 4; ++r) {
                int row = bm + wr * 64 + mi * 16 + quad * 4 + r;
                int col = bn + wc * 32 + ni * 16 + lq;
                out[(size_t)row * CC + col] = acc[mi][ni][r];
            }
}

// ---------------- Launch ----------------
extern "C" void kernel_launch(void* const* d_in, const int* in_sizes, int n_in,
                              void* d_out, int out_size, void* d_ws, size_t ws_size,
                              hipStream_t stream) {
    const float* inputs_q  = (const float*)d_in[0];
    const float* inputs_kv = (const float*)d_in[1];
    const float* Wq   = (const float*)d_in[2];
    const float* Wk   = (const float*)d_in[3];
    const float* Wv   = (const float*)d_in[4];
    const float* Wout = (const float*)d_in[5];
    const float* Wpre  = (const float*)d_in[6];
    const float* Wpost = (const float*)d_in[7];
    float* out = (float*)d_out;

    const size_t nS   = (size_t)BB * HH * LL * LL;   // E: [b][k][l][12]
    const size_t nQKV = (size_t)BB * HH * LL * DD;
    const size_t nW   = (size_t)CC * CC;

    ushort_t* Eb   = (ushort_t*)d_ws;
    ushort_t* Qb   = Eb + nS;
    ushort_t* Kb   = Qb + nQKV;
    ushort_t* Vtb  = Kb + nQKV;
    ushort_t* attb = Vtb + nQKV;
    ushort_t* inq  = attb + nQKV;
    ushort_t* inkv = inq + nQKV;
    ushort_t* Wqt  = inkv + nQKV;
    ushort_t* Wkt  = Wqt + nW;
    ushort_t* Wvt  = Wkt + nW;
    ushort_t* Wot  = Wvt + nW;
    float*    Zb   = (float*)(Wot + nW);             // [b][h][l] fp32, 192KB

    dim3 blk(256);

    prep<<<dim3(5568), blk, 0, stream>>>(inputs_q, inputs_kv, Wq, Wk, Wv, Wout,
                                         inq, inkv, Wqt, Wkt, Wvt, Wot, Zb);
    proj_gemm<<<dim3(32, 6, 3), blk, 0, stream>>>(inq, inkv, Wqt, Wkt, Wvt, Qb, Kb, Vtb);
    qk_premix<<<dim3(4096), blk, 0, stream>>>(Qb, Kb, Wpre, Eb, Zb);
    pv_postmix<<<dim3(512), blk, 0, stream>>>(Eb, Vtb, Wpost, Zb, attb);
    out_gemm<<<dim3(32, 12), blk, 0, stream>>>(attb, Wot, out);
}

// Round 6
// 250.644 us; speedup vs baseline: 1.0586x; 1.0557x over previous
//
#include <hip/hip_runtime.h>
#include <hip/hip_bf16.h>

#define BB 4
#define LL 1024
#define CC 768
#define HH 12
#define DD 64

typedef unsigned short ushort_t;
typedef __attribute__((ext_vector_type(8))) short bf16x8;
typedef __attribute__((ext_vector_type(4))) float f32x4;
typedef __attribute__((ext_vector_type(2))) float f32x2;
typedef __attribute__((ext_vector_type(2))) unsigned u32x2;

__device__ inline ushort_t f2bf(float x) {
    union { float f; unsigned u; } v; v.f = x;
    unsigned r = (v.u + 0x7FFFu + ((v.u >> 16) & 1u)) >> 16;
    return (ushort_t)r;
}
__device__ inline float u2f(unsigned u) {
    union { unsigned u; float f; } v; v.u = u;
    return v.f;
}
// pack two f32 -> packed 2xbf16 (RNE) via the HW cvt_pk path
__device__ inline unsigned pack2bf(float lo, float hi) {
    union { __hip_bfloat162 v; unsigned u; } r;
    r.v = __float22bfloat162_rn(make_float2(lo, hi));
    return r.u;
}

// Stage rows x 32 shorts from g (row stride `stride` shorts) into LDS,
// contiguous 64B rows, via async global->LDS (16B/lane, wave-uniform LDS base).
__device__ inline void stage_rows(const ushort_t* __restrict__ g, int stride,
                                  ushort_t* lds, int nbytes, int wave, int lane) {
    const int ko = (lane & 3) << 3;
    const int rsub = lane >> 2;
    for (int off = wave * 1024; off < nbytes; off += 4096) {
        int row = (off >> 6) + rsub;
        __builtin_amdgcn_global_load_lds(
            (const __attribute__((address_space(1))) void*)(g + (size_t)row * stride + ko),
            (__attribute__((address_space(3))) void*)(lds + (off >> 1)),
            16, 0, 0);
    }
}

// ---------------- prep: cast inputs + cast/transpose weights + zero Z (one launch) --------
__global__ __launch_bounds__(256) void prep(const float* __restrict__ q, const float* __restrict__ kv,
                                            const float* __restrict__ w0, const float* __restrict__ w1,
                                            const float* __restrict__ w2, const float* __restrict__ w3,
                                            ushort_t* __restrict__ qo, ushort_t* __restrict__ kvo,
                                            ushort_t* __restrict__ o0, ushort_t* __restrict__ o1,
                                            ushort_t* __restrict__ o2, ushort_t* __restrict__ o3,
                                            float* __restrict__ Zp) {
    __shared__ float t[32][33];
    const int bx = blockIdx.x;
    if (bx < 3072) {
        const float* src = bx < 1536 ? q : kv;
        ushort_t* dst = bx < 1536 ? qo : kvo;
        int bb = bx < 1536 ? bx : bx - 1536;
        size_t i = ((size_t)bb * 256 + threadIdx.x) * 8;
        float4 a = *(const float4*)(src + i);
        float4 b = *(const float4*)(src + i + 4);
        ushort_t u[8] = {f2bf(a.x), f2bf(a.y), f2bf(a.z), f2bf(a.w),
                         f2bf(b.x), f2bf(b.y), f2bf(b.z), f2bf(b.w)};
        *(uint4*)(dst + i) = *(uint4*)u;
    } else if (bx < 5376) {
        int w = bx - 3072;
        int z = w / 576, rem = w % 576;
        const float* W = z == 0 ? w0 : z == 1 ? w1 : z == 2 ? w2 : w3;
        ushort_t* Wt   = z == 0 ? o0 : z == 1 ? o1 : z == 2 ? o2 : o3;
        const int c = threadIdx.x & 31, r0 = threadIdx.x >> 5;
        const int kb = (rem / 24) * 32, nb = (rem % 24) * 32;
#pragma unroll
        for (int i = 0; i < 4; ++i)
            t[r0 + 8 * i][c] = W[(size_t)(kb + r0 + 8 * i) * CC + nb + c];
        __syncthreads();
#pragma unroll
        for (int i = 0; i < 4; ++i)
            Wt[(size_t)(nb + r0 + 8 * i) * CC + kb + c] = f2bf(t[c][r0 + 8 * i]);
    } else {
        // zero softmax denominators: 4*12*1024 floats over 192 blocks
        Zp[(bx - 5376) * 256 + threadIdx.x] = 0.f;
    }
}

// ---------------- fused Q/K/V projection (MFMA bf16), z picks target ----------------
// Q and K are written PRE-TILED in MFMA-fragment order:
//   per (b,h) plane of 64K elems: off = ((l>>4)*8 + (d>>3))*128 + (l&15)*8 + (d&7)
// so qk_premix can load fragments as contiguous 1KB wave-reads with no LDS.
__global__ __launch_bounds__(256) void proj_gemm(const ushort_t* __restrict__ Aq,
                                                 const ushort_t* __restrict__ Akv,
                                                 const ushort_t* __restrict__ Wqt,
                                                 const ushort_t* __restrict__ Wkt,
                                                 const ushort_t* __restrict__ Wvt,
                                                 ushort_t* __restrict__ Qo,
                                                 ushort_t* __restrict__ Ko,
                                                 ushort_t* __restrict__ Vto) {
    const int z = blockIdx.z;
    const ushort_t* A  = (z == 0) ? Aq : Akv;
    const ushort_t* Wt = (z == 0) ? Wqt : (z == 1 ? Wkt : Wvt);

    __shared__ __align__(16) ushort_t a_lds[128 * 32];
    __shared__ __align__(16) ushort_t b_lds[128 * 32];

    const int tid = threadIdx.x;
    const int bm = blockIdx.x * 128, bn = blockIdx.y * 128;
    const int wave = tid >> 6, lane = tid & 63;
    const int quad = lane >> 4, lq = lane & 15;
    const int wr = wave >> 1, wc = wave & 1;

    f32x4 acc[4][4] = {};

    for (int k0 = 0; k0 < CC; k0 += 32) {
        stage_rows(A + (size_t)bm * CC + k0, CC, a_lds, 8192, wave, lane);
        stage_rows(Wt + (size_t)bn * CC + k0, CC, b_lds, 8192, wave, lane);
        __syncthreads();
        bf16x8 af[4], bfr[4];
#pragma unroll
        for (int mi = 0; mi < 4; ++mi)
            af[mi] = *(bf16x8*)&a_lds[(wr * 64 + mi * 16 + lq) * 32 + quad * 8];
#pragma unroll
        for (int ni = 0; ni < 4; ++ni)
            bfr[ni] = *(bf16x8*)&b_lds[(wc * 64 + ni * 16 + lq) * 32 + quad * 8];
#pragma unroll
        for (int mi = 0; mi < 4; ++mi)
#pragma unroll
            for (int ni = 0; ni < 4; ++ni)
                acc[mi][ni] = __builtin_amdgcn_mfma_f32_16x16x32_bf16(af[mi], bfr[ni], acc[mi][ni], 0, 0, 0);
        __syncthreads();
    }

    const float scale = (z == 0) ? 0.125f : 1.0f;
#pragma unroll
    for (int mi = 0; mi < 4; ++mi)
#pragma unroll
        for (int ni = 0; ni < 4; ++ni)
#pragma unroll
            for (int r = 0; r < 4; ++r) {
                int row = bm + wr * 64 + mi * 16 + quad * 4 + r;  // b*1024 + l(or k)
                int col = bn + wc * 64 + ni * 16 + lq;            // h*64 + d
                int b = row >> 10, l = row & 1023, h = col >> 6, d = col & 63;
                ushort_t v = f2bf(acc[mi][ni][r] * scale);
                if (z == 2) {
                    Vto[((size_t)(b * HH + h) * DD + d) * LL + l] = v;
                } else {
                    size_t off = (size_t)(b * HH + h) * (LL * DD)
                               + (size_t)(((l >> 4) * 8 + (d >> 3)) * 128 + (l & 15) * 8 + (d & 7));
                    if (z == 0) Qo[off] = v;
                    else        Ko[off] = v;
                }
            }
}

// ---------------- QK^T fused with premix + exp + denominator accumulation ----------------
// Barrier-free, LDS-free. E stored bf16 in PV-friendly tiled layout:
//   E[b][lt][k][li][h], lt = l>>4, li = l&15  (each pv block's slice is 384KB contiguous)
__global__ __launch_bounds__(256) void qk_premix(const ushort_t* __restrict__ Qf,
                                                 const ushort_t* __restrict__ Kf,
                                                 const float* __restrict__ Wpre,
                                                 ushort_t* __restrict__ E,
                                                 float* __restrict__ Z) {
    const int tid = threadIdx.x;
    const int lane = tid & 63, wave = tid >> 6;
    const int quad = lane >> 4, lq = lane & 15;
    const int wr = wave >> 1, wc = wave & 1;

    // XCD-aware decode: xcd = x%8 (round-robin dispatch); each XCD-pair owns one b.
    const int x = blockIdx.x;
    const int xcd = x & 7;
    const int b = xcd >> 1;                           // 0..3
    const int s = x >> 3;                             // 0..511
    const int bk = (s & 31) << 5;                     // k-tile base
    const int bl = ((((s >> 5) << 1) | (xcd & 1))) << 5;  // l-tile base

    // fragment bases: per (b,h) plane LL*DD elems; k16-block = 1024 elems (2KB)
    const ushort_t* Kp = Kf + (size_t)b * HH * LL * DD
                       + (size_t)(((bk >> 4) + wr) * 1024 + quad * 128 + lq * 8);
    const ushort_t* Qp = Qf + (size_t)b * HH * LL * DD
                       + (size_t)(((bl >> 4) + wc) * 1024 + quad * 128 + lq * 8);

    f32x4 acc[HH] = {};
#pragma unroll
    for (int h = 0; h < HH; ++h) {
        const size_t ho = (size_t)h * (LL * DD);
        bf16x8 ka0 = *(const bf16x8*)(Kp + ho);
        bf16x8 ka1 = *(const bf16x8*)(Kp + ho + 512);
        bf16x8 qb0 = *(const bf16x8*)(Qp + ho);
        bf16x8 qb1 = *(const bf16x8*)(Qp + ho + 512);
        acc[h] = __builtin_amdgcn_mfma_f32_16x16x32_bf16(ka0, qb0, acc[h], 0, 0, 0);
        acc[h] = __builtin_amdgcn_mfma_f32_16x16x32_bf16(ka1, qb1, acc[h], 0, 0, 0);
    }

    // premix (fp32, thread-local across heads) + exp + pack bf16 pairs (heads 2i,2i+1)
    unsigned pk[6][4];
#pragma unroll
    for (int i2 = 0; i2 < 6; ++i2) {
        f32x4 m0 = {}, m1 = {};
#pragma unroll
        for (int h = 0; h < HH; ++h) {
            m0 += acc[h] * Wpre[h * HH + 2 * i2];
            m1 += acc[h] * Wpre[h * HH + 2 * i2 + 1];
        }
#pragma unroll
        for (int r = 0; r < 4; ++r)
            pk[i2][r] = pack2bf(__expf(m0[r]), __expf(m1[r]));
    }

    // denominator partials from ROUNDED values: sum this thread's 4 k-rows,
    // reduce across quads (k groups), atomically add per (i, l).
    float zp[HH];
#pragma unroll
    for (int i2 = 0; i2 < 6; ++i2) {
        float s0 = 0.f, s1 = 0.f;
#pragma unroll
        for (int r = 0; r < 4; ++r) {
            s0 += u2f(pk[i2][r] << 16);
            s1 += u2f(pk[i2][r] & 0xFFFF0000u);
        }
        zp[2 * i2] = s0; zp[2 * i2 + 1] = s1;
    }
#pragma unroll
    for (int i = 0; i < HH; ++i) {
        zp[i] += __shfl_xor(zp[i], 16);
        zp[i] += __shfl_xor(zp[i], 32);
    }
    if (quad == 0) {
#pragma unroll
        for (int i = 0; i < HH; ++i)
            atomicAdd(&Z[((size_t)b * HH + i) * LL + bl + wc * 16 + lq], zp[i]);
    }

    // store E[b][lt][k][li][12], NT (don't evict Q/K from L2)
    const int ltw = (bl >> 4) + wc;   // l-tile index of this thread's column
#pragma unroll
    for (int r = 0; r < 4; ++r) {
        const int k = bk + wr * 16 + quad * 4 + r;
        ushort_t* ep = E + (((size_t)(b * 64 + ltw) * 1024 + k) * 16 + lq) * 12;
        u32x2 s0; s0.x = pk[0][r]; s0.y = pk[1][r];
        u32x2 s1; s1.x = pk[2][r]; s1.y = pk[3][r];
        u32x2 s2; s2.x = pk[4][r]; s2.y = pk[5][r];
        __builtin_nontemporal_store(s0, (u32x2*)ep);
        __builtin_nontemporal_store(s1, (u32x2*)(ep + 4));
        __builtin_nontemporal_store(s2, (u32x2*)(ep + 8));
    }
}

// ---------------- PV fused with normalize + postmix (v4: DMA-streamed E) ----------------
// Block = (b, 16 l-rows, head-group of 6), 256 threads / 4 waves. Grid 512 (2 blk/CU).
// E slice [1024 k][16 l][12 h] is contiguous per block; per kt each WAVE stages its OWN
// 6KB k-range via global_load_lds (no barrier needed for e_lds), counted vmcnt keeps the
// pipeline 1 kt deep (never drains to 0). V fragments prefetch to regs under postmix.
// Only barrier per kt is lgkm-only for p_lds.
__global__ __launch_bounds__(256, 2) void pv_postmix(const ushort_t* __restrict__ E,
                                                     const ushort_t* __restrict__ Vt,
                                                     const float* __restrict__ Wpost,
                                                     const float* __restrict__ Z,
                                                     ushort_t* __restrict__ att) {
    __shared__ __align__(16) ushort_t e_lds[2][64 * 16 * 12];  // 2 x 24KB [k64][l16][h12]
    __shared__ __align__(16) ushort_t p_lds[2][6 * 16 * 64];   // 2 x 12KB, XOR-swizzled

    const int tid = threadIdx.x;
    const int lane = tid & 63, wave = tid >> 6;
    const int quad = lane >> 4, lq = lane & 15;
    const int wd = wave;                       // d-quadrant (16 cols)
    const int lmix = tid & 15, kp = tid >> 4;  // mixing role: l row, k-quad (kp = wave*4 + lane>>4)

    // decode: 512 blocks; xcd = bid&7 -> b; s = bid>>3: hg = s>>5, lt = (s&31)*2+(xcd&1)
    const int bid = blockIdx.x;
    const int xcd = bid & 7;
    const int b = xcd >> 1;
    const int s = bid >> 3;
    const int hg = s >> 5;                     // head-group 0/1
    const int ig = hg * 6;
    const int lt = ((s & 31) << 1) | (xcd & 1);
    const int bl = lt << 4;

    float invZ[HH];
#pragma unroll
    for (int h = 0; h < HH; ++h)
        invZ[h] = 1.0f / Z[((size_t)b * HH + h) * LL + bl + lmix];

    // contiguous E slice for this (b, lt): 1024 k x 192 elems
    const ushort_t* eslice = E + (size_t)(b * 64 + lt) * 1024 * 192;
    // V base: output head ig+ii uses V[ig+ii]; this wave covers d = wd*16+lq
    const size_t vbase = ((size_t)(b * HH + ig) * DD + wd * 16 + lq) * LL;

    f32x4 acc[6] = {};

    // wave stages its OWN 6KB k-range [kt*64 + wave*16, +16) -> no barrier for e_lds
#define ESTAGE(kt_, buf_)                                                                      \
    do {                                                                                       \
        const ushort_t* sb_ = eslice + (size_t)((kt_)*64 + wave * 16) * 192;                   \
        ushort_t* db_ = &e_lds[buf_][wave * 3072];                                             \
        _Pragma("unroll")                                                                      \
        for (int j_ = 0; j_ < 6; ++j_)                                                         \
            __builtin_amdgcn_global_load_lds(                                                  \
                (const __attribute__((address_space(1))) void*)(sb_ + j_ * 512 + lane * 8),    \
                (__attribute__((address_space(3))) void*)(db_ + j_ * 512 + lane * 8),          \
                16, 0, 0);                                                                     \
    } while (0)

    ESTAGE(0, 0);

#pragma unroll 1
    for (int kt = 0; kt < 16; ++kt) {
        // ---- V fragment prefetch to regs (L2-resident; latency hides under postmix)
        bf16x8 vf[12];
#pragma unroll
        for (int k0 = 0; k0 < 2; ++k0)
#pragma unroll
            for (int ii = 0; ii < 6; ++ii)
                vf[k0 * 6 + ii] = *(const bf16x8*)(Vt + vbase + (size_t)ii * (DD * LL)
                                                   + kt * 64 + k0 * 32 + quad * 8);

        // ---- issue next E stage, then counted wait: newest 18 = {12 V, 6 stage(kt+1)}
        // stay in flight; everything older (stage(kt)) retires -> own e_lds region ready.
        if (kt < 15) {
            ESTAGE(kt + 1, (kt + 1) & 1);
            asm volatile("s_waitcnt vmcnt(18)" ::: "memory");
        } else {
            asm volatile("s_waitcnt vmcnt(12)" ::: "memory");
        }
        __builtin_amdgcn_sched_barrier(0);

        // ---- postmix from e_lds (wave-own region): normalize + mix 12 in -> 6 out heads
        const ushort_t* eb = e_lds[kt & 1];
        unsigned pkw[2][6];
#pragma unroll
        for (int u = 0; u < 2; ++u) {
            const ushort_t* ebp = eb + ((kp * 4 + 2 * u) - wave * 16) * 192 + wave * 3072 + lmix * 12;
            u32x2 e0 = *(const u32x2*)(ebp);
            u32x2 e1 = *(const u32x2*)(ebp + 4);
            u32x2 e2 = *(const u32x2*)(ebp + 8);
            u32x2 o0 = *(const u32x2*)(ebp + 192);
            u32x2 o1 = *(const u32x2*)(ebp + 196);
            u32x2 o2 = *(const u32x2*)(ebp + 200);
            unsigned w0[6] = {e0.x, e0.y, e1.x, e1.y, e2.x, e2.y};
            unsigned w1[6] = {o0.x, o0.y, o1.x, o1.y, o2.x, o2.y};
            f32x2 m[6] = {};
#pragma unroll
            for (int h2 = 0; h2 < 6; ++h2) {
                f32x2 pe, po;
                pe.x = u2f(w0[h2] << 16);           pe.y = u2f(w1[h2] << 16);
                po.x = u2f(w0[h2] & 0xFFFF0000u);   po.y = u2f(w1[h2] & 0xFFFF0000u);
                pe *= invZ[2 * h2];
                po *= invZ[2 * h2 + 1];
#pragma unroll
                for (int i = 0; i < 6; ++i) {
                    m[i] += pe * Wpost[(2 * h2) * HH + ig + i];
                    m[i] += po * Wpost[(2 * h2 + 1) * HH + ig + i];
                }
            }
#pragma unroll
            for (int i = 0; i < 6; ++i) pkw[u][i] = pack2bf(m[i].x, m[i].y);
        }

        // ---- write mixed P to swizzled LDS (buf = kt&1); word w = kp*2+u per row
        {
            unsigned* pw = (unsigned*)p_lds[kt & 1];
#pragma unroll
            for (int u = 0; u < 2; ++u) {
                const int w = kp * 2 + u;
                const int word = (((w >> 2) ^ (lmix & 7)) << 2) + (w & 3);
#pragma unroll
                for (int i = 0; i < 6; ++i)
                    pw[(i * 16 + lmix) * 32 + word] = pkw[u][i];
            }
        }

        // ---- raw barrier: drain LDS ops only; global/DMA loads stay in flight
        asm volatile("s_waitcnt lgkmcnt(0)" ::: "memory");
        __builtin_amdgcn_s_barrier();
        asm volatile("" ::: "memory");

        // ---- MFMA: O_i[16 l][16 d] += P_i x V_i over K=64 (V already in regs)
        const ushort_t* pb = p_lds[kt & 1];
#pragma unroll
        for (int k0 = 0; k0 < 2; ++k0) {
            const int chs = ((k0 << 2) + quad) ^ (lq & 7);
#pragma unroll
            for (int ii = 0; ii < 6; ++ii) {
                bf16x8 pa = *(bf16x8*)&pb[(ii * 16 + lq) * 64 + chs * 8];
                acc[ii] = __builtin_amdgcn_mfma_f32_16x16x32_bf16(pa, vf[k0 * 6 + ii], acc[ii], 0, 0, 0);
            }
        }
    }
#undef ESTAGE

#pragma unroll
    for (int ii = 0; ii < 6; ++ii)
#pragma unroll
        for (int r = 0; r < 4; ++r)
            att[((size_t)b * LL + bl + quad * 4 + r) * CC + (ig + ii) * 64 + wd * 16 + lq] =
                f2bf(acc[ii][r]);
}

// ---------------- out = att @ Wout (MFMA, fp32 out). BM=128, BN=64 -> 384 blocks ----------------
__global__ __launch_bounds__(256) void out_gemm(const ushort_t* __restrict__ A,
                                                const ushort_t* __restrict__ Wt,
                                                float* __restrict__ out) {
    __shared__ __align__(16) ushort_t a_lds[128 * 32];
    __shared__ __align__(16) ushort_t b_lds[64 * 32];

    const int tid = threadIdx.x;
    const int bm = blockIdx.x * 128, bn = blockIdx.y * 64;
    const int wave = tid >> 6, lane = tid & 63;
    const int quad = lane >> 4, lq = lane & 15;
    const int wr = wave >> 1, wc = wave & 1;

    f32x4 acc[4][2] = {};

    for (int k0 = 0; k0 < CC; k0 += 32) {
        stage_rows(A + (size_t)bm * CC + k0, CC, a_lds, 8192, wave, lane);
        stage_rows(Wt + (size_t)bn * CC + k0, CC, b_lds, 4096, wave, lane);
        __syncthreads();
        bf16x8 af[4], bfr[2];
#pragma unroll
        for (int mi = 0; mi < 4; ++mi)
            af[mi] = *(bf16x8*)&a_lds[(wr * 64 + mi * 16 + lq) * 32 + quad * 8];
#pragma unroll
        for (int ni = 0; ni < 2; ++ni)
            bfr[ni] = *(bf16x8*)&b_lds[(wc * 32 + ni * 16 + lq) * 32 + quad * 8];
#pragma unroll
        for (int mi = 0; mi < 4; ++mi)
#pragma unroll
            for (int ni = 0; ni < 2; ++ni)
                acc[mi][ni] = __builtin_amdgcn_mfma_f32_16x16x32_bf16(af[mi], bfr[ni], acc[mi][ni], 0, 0, 0);
        __syncthreads();
    }

#pragma unroll
    for (int mi = 0; mi < 4; ++mi)
#pragma unroll
        for (int ni = 0; ni < 2; ++ni)
#pragma unroll
            for (int r = 0; r < 4; ++r) {
                int row = bm + wr * 64 + mi * 16 + quad * 4 + r;
                int col = bn + wc * 32 + ni * 16 + lq;
                out[(size_t)row * CC + col] = acc[mi][ni][r];
            }
}

// ---------------- Launch ----------------
extern "C" void kernel_launch(void* const* d_in, const int* in_sizes, int n_in,
                              void* d_out, int out_size, void* d_ws, size_t ws_size,
                              hipStream_t stream) {
    const float* inputs_q  = (const float*)d_in[0];
    const float* inputs_kv = (const float*)d_in[1];
    const float* Wq   = (const float*)d_in[2];
    const float* Wk   = (const float*)d_in[3];
    const float* Wv   = (const float*)d_in[4];
    const float* Wout = (const float*)d_in[5];
    const float* Wpre  = (const float*)d_in[6];
    const float* Wpost = (const float*)d_in[7];
    float* out = (float*)d_out;

    const size_t nS   = (size_t)BB * HH * LL * LL;   // E: [b][lt][k][li][12]
    const size_t nQKV = (size_t)BB * HH * LL * DD;
    const size_t nW   = (size_t)CC * CC;

    ushort_t* Eb   = (ushort_t*)d_ws;
    ushort_t* Qb   = Eb + nS;
    ushort_t* Kb   = Qb + nQKV;
    ushort_t* Vtb  = Kb + nQKV;
    ushort_t* attb = Vtb + nQKV;
    ushort_t* inq  = attb + nQKV;
    ushort_t* inkv = inq + nQKV;
    ushort_t* Wqt  = inkv + nQKV;
    ushort_t* Wkt  = Wqt + nW;
    ushort_t* Wvt  = Wkt + nW;
    ushort_t* Wot  = Wvt + nW;
    float*    Zb   = (float*)(Wot + nW);             // [b][h][l] fp32, 192KB

    dim3 blk(256);

    prep<<<dim3(5568), blk, 0, stream>>>(inputs_q, inputs_kv, Wq, Wk, Wv, Wout,
                                         inq, inkv, Wqt, Wkt, Wvt, Wot, Zb);
    proj_gemm<<<dim3(32, 6, 3), blk, 0, stream>>>(inq, inkv, Wqt, Wkt, Wvt, Qb, Kb, Vtb);
    qk_premix<<<dim3(4096), blk, 0, stream>>>(Qb, Kb, Wpre, Eb, Zb);
    pv_postmix<<<dim3(512), blk, 0, stream>>>(Eb, Vtb, Wpost, Zb, attb);
    out_gemm<<<dim3(32, 12), blk, 0, stream>>>(attb, Wot, out);
}